// Round 11
// baseline (146.868 us; speedup 1.0000x reference)
//
#include <hip/hip_runtime.h>
#include <hip/hip_bf16.h>
#include <math.h>

// Problem constants
#define L_SEQ   1024
#define NB      8
#define H_DIM   300
#define KWIN    5
#define NREL    11          // 2K+1
#define PDIM    50
#define NC      11234       // band pair count for L=1024, K=5
#define BNC     (NB*NC)     // 89872
#define LN_EPS  1e-5f

#define KPAD    320         // K padded with zeros in [300,320)
#define WKSTR   320         // Wb k-stride (shorts)
#define WNPAD   320         // Wb padded n rows

#define ITILE   16          // i rows per block
#define HROWS   26          // hc halo rows: i0-5 .. i0+20
#define ZROW    42          // LDS zero row index
#define XROWS   43          // 0..15 he, 16..41 hc, 42 zero
#define XSTR    328         // X row stride in shorts
#define PRELSTR 320         // padded prel row stride (floats)
#define NPAIR   (ITILE*NREL)  // 176

// Workspace layout (float offsets)
#define PREL_OFF  0                         // 11*320 = 3520 -> pad 3584
#define WB_OFF    3584                      // 2*320*320 shorts = 102400 floats

typedef __attribute__((ext_vector_type(8))) short s16x8;
typedef __attribute__((ext_vector_type(4))) short s16x4;
typedef __attribute__((ext_vector_type(4))) float f32x4;

__device__ __forceinline__ short f2bf(float f) {
    unsigned u = __float_as_uint(f);
    u += 0x7fffu + ((u >> 16) & 1u);
    return (short)(u >> 16);
}
__device__ __forceinline__ float bf2f(short s) {
    return __uint_as_float(((unsigned)(unsigned short)s) << 16);
}

// band row start: first linear index n of row i
__device__ __forceinline__ int rowstart(int i) {
    if (i < 5)     return 6 * i + (i * (i - 1)) / 2;
    if (i <= 1018) return 40 + (i - 5) * 11;
    int d = i - 1019;
    return 11194 + d * 10 - (d * (d - 1)) / 2;
}

// ---------------------------------------------------------------------------
// Kernel 1: prep.
//  blocks 0..13   : prelP[r][h] (stride 320, zero pad h>=300)
//  blocks 14..813 : Wb[z][n][k] = bf16(W1[n][z*300+k]), zero-padded
__global__ __launch_bounds__(256) void prep_kernel(
    const float* __restrict__ pos_W, const float* __restrict__ W1,
    const float* __restrict__ b1, float* __restrict__ prel,
    short* __restrict__ Wb)
{
    if (blockIdx.x < 14) {
        __shared__ float semb[NREL * PDIM];
        for (int t = threadIdx.x; t < NREL * PDIM; t += 256) {
            int r = t / PDIM, d = t % PDIM;
            float acc = 0.f;
#pragma unroll
            for (int r2 = 0; r2 < NREL; ++r2) {
                float cnt = (float)(L_SEQ - abs(r2 - KWIN));
                int dr = r - r2;
                acc += cnt * expf(-(float)(dr * dr)) * pos_W[r2 * PDIM + d];
            }
            semb[t] = acc;
        }
        __syncthreads();
        int t = blockIdx.x * 256 + threadIdx.x;
        if (t < NREL * PRELSTR) {
            int r = t / PRELSTR, h = t % PRELSTR;
            float acc = 0.f;
            if (h < H_DIM) {
                acc = b1[h];
                const float* wrow = W1 + (size_t)h * 650 + 600;
                const float* em = semb + r * PDIM;
#pragma unroll 10
                for (int d = 0; d < PDIM; ++d) acc += wrow[d] * em[d];
            }
            prel[t] = acc;
        }
    } else {
        int id = (blockIdx.x - 14) * 256 + threadIdx.x;
        if (id < 2 * WNPAD * WKSTR) {
            int z = id / (WNPAD * WKSTR);
            int rem = id % (WNPAD * WKSTR);
            int n = rem / WKSTR, k = rem % WKSTR;
            float v = (n < H_DIM && k < H_DIM) ? W1[(size_t)n * 650 + z * H_DIM + k] : 0.f;
            Wb[id] = f2bf(v);
        }
    }
}

// ---------------------------------------------------------------------------
// Kernel 2: fused GEMM + epilogue. Block = (b, i-tile of 16). 1024 threads
// (16 waves). Grid 512 -> 2 blocks/CU x 16 waves = 32 waves/CU (HW max).
// LDS 46 KB/block -> 2 resident. One m-frag per GEMM wave -> VGPR ~50.
__global__ __launch_bounds__(1024) void fused_kernel(
    const float* __restrict__ h_e, const float* __restrict__ h_c,
    const float* __restrict__ h_share, const short* __restrict__ Wb,
    const float* __restrict__ prel,
    const float* __restrict__ ln_g, const float* __restrict__ ln_b,
    const float* __restrict__ W2, const float* __restrict__ b2,
    float* __restrict__ out, float* __restrict__ posout)
{
    __shared__ __align__(16) short X[XROWS * XSTR];    // 28208 B
    __shared__ __align__(16) float PL[NREL * PRELSTR]; // 14080 B
    __shared__ __align__(16) float SG[PRELSTR];
    __shared__ __align__(16) float SB[PRELSTR];
    __shared__ __align__(16) float SW[PRELSTR];

    const int tid = threadIdx.x;
    const int b   = blockIdx.x >> 6;          // 64 i-tiles per batch
    const int i0  = (blockIdx.x & 63) * ITILE;

    // ---- zero-fill: all 43 rows cols [304,328) (129) + zero row [0,304) (38)
    for (int t = tid; t < 167; t += 1024) {
        int row, c;
        if (t < 129) { row = t / 3;  c = 304 + (t % 3) * 8; }
        else         { row = ZROW;   c = (t - 129) * 8; }
        *(s16x8*)&X[row * XSTR + c] = (s16x8){0,0,0,0,0,0,0,0};
    }
    // ---- prel -> LDS (880 float4 chunks)
    for (int t = tid; t < NREL * 80; t += 1024) {
        int r = t / 80, kc = (t % 80) * 4;
        *(float4*)&PL[r * PRELSTR + kc] = *(const float4*)(prel + r * PRELSTR + kc);
    }
    // ---- LN params to LDS (zero pad to 320)
    if (tid < PRELSTR) {
        bool v = tid < H_DIM;
        SG[tid] = v ? ln_g[tid] : 0.f;
        SB[tid] = v ? ln_b[tid] : 0.f;
        SW[tid] = v ? W2[tid]   : 0.f;
    }
    // ---- stage 26 halo rows; h_share read once per row.
    //  X rows 16..41 = bf16(hc+hs)[i0-5+s]; rows 0..15 = bf16(he+hs)[i0+(s-5)]
    for (int t = tid; t < HROWS * 76; t += 1024) {
        int s = t / 76, kc = (t % 76) * 4;
        int g = i0 - KWIN + s;
        bool valid = (kc < H_DIM) && (g >= 0) && (g < L_SEQ);
        float4 hs4 = make_float4(0.f,0.f,0.f,0.f), hc4 = hs4;
        size_t off = 0;
        if (valid) {
            off = ((size_t)b * L_SEQ + g) * H_DIM + kc;
            hs4 = *(const float4*)(h_share + off);
            hc4 = *(const float4*)(h_c + off);
        }
        s16x4 vc = { f2bf(hc4.x + hs4.x), f2bf(hc4.y + hs4.y),
                     f2bf(hc4.z + hs4.z), f2bf(hc4.w + hs4.w) };
        *(s16x4*)&X[(16 + s) * XSTR + kc] = vc;
        if (s >= 5 && s < 5 + ITILE) {         // he row: g = i0 + (s-5)
            float4 he4 = make_float4(0.f,0.f,0.f,0.f);
            if (valid) he4 = *(const float4*)(h_e + off);
            s16x4 ve = { f2bf(he4.x + hs4.x), f2bf(he4.y + hs4.y),
                         f2bf(he4.z + hs4.z), f2bf(he4.w + hs4.w) };
            *(s16x4*)&X[(s - 5) * XSTR + kc] = ve;
        }
    }
    __syncthreads();

    // ---- GEMM. 16 waves = (mg, nsl): mg = wave>>2 (m-group), nsl = (wave&3)*80.
    //  mg0: he rows 0..15 (z=0). mg1: hc rows 16..31 (z=1).
    //  mg2: hc rows 32..41 + zero clamp (z=1). mg3: idle.
    const int wave = tid >> 6, lane = tid & 63;
    const int fr = lane & 15, fq = lane >> 4;
    const int mg  = wave >> 2;
    const int nsl = (wave & 3) * 80;
    const int wz  = (mg > 0) ? 1 : 0;
    const short* wbase = Wb + ((size_t)(wz * WNPAD + nsl + fr)) * WKSTR + fq * 8;

    const int mrow = (mg == 0) ? fr
                   : (mg == 1) ? (16 + fr)
                   :             ((fr < 10) ? 32 + fr : ZROW);

    f32x4 acc[5] = {};

    if (mg < 3) {
        for (int k0 = 0; k0 < KPAD; k0 += 32) {
            s16x8 bf[5];
#pragma unroll
            for (int nt = 0; nt < 5; ++nt)
                bf[nt] = *(const s16x8*)(wbase + (size_t)nt * 16 * WKSTR + k0);
            s16x8 af = *(const s16x8*)&X[mrow * XSTR + k0 + fq * 8];
#pragma unroll
            for (int nt = 0; nt < 5; ++nt)
                acc[nt] = __builtin_amdgcn_mfma_f32_16x16x32_bf16(af, bf[nt], acc[nt], 0, 0, 0);
        }
    }
    __syncthreads();   // all waves done reading X inputs

    // ---- write results into X (bf16). C/D: col = nsl+nt*16+fr, row = fq*4+r2.
    if (mg < 3) {
#pragma unroll
        for (int nt = 0; nt < 5; ++nt) {
            const int col = nsl + nt * 16 + fr;   // cols>=300 compute to 0
            const int rb = mg * 16 + fq * 4;
#pragma unroll
            for (int r2 = 0; r2 < 4; ++r2) {
                const int rw = rb + r2;
                if (mg < 2 || rw < 42) X[rw * XSTR + col] = f2bf(acc[nt][r2]);
            }
        }
    }
    __syncthreads();

    // ---- Epilogue: 1 pair per 16-lane quad, 64 quads, 3 rounds (176 pairs).
    const int quad = lane >> 4, fl = lane & 15;
    const int qq = wave * 4 + quad;            // 0..63
    const float b2v = b2[0];
    const float inv = 1.f / (float)H_DIM;

    for (int round = 0; round < 3; ++round) {
        const int q = round * 64 + qq;          // 0..191
        const int qc = q < NPAIR - 1 ? q : NPAIR - 1;
        const int di = qc / NREL, rr = qc % NREL;
        const int ii = i0 + di, j = ii - KWIN + rr;
        const bool active = (q < NPAIR) && (j >= 0) && (j < L_SEQ);

        const int ea = di * XSTR;               // he rows 0..15
        const int ca = (16 + di + rr) * XSTR;   // hc rows 16..41
        const float* prow = PL + rr * PRELSTR;

        float h[20];
        float s = 0.f, ss = 0.f;
#pragma unroll
        for (int w5 = 0; w5 < 5; ++w5) {
            const int c = w5 * 64 + fl * 4;     // 0..316, zero-padded
            s16x4 a0 = *(const s16x4*)&X[ea + c];
            s16x4 d0 = *(const s16x4*)&X[ca + c];
            float4 p0 = *(const float4*)(prow + c);
#pragma unroll
            for (int e = 0; e < 4; ++e) {
                float v = bf2f(a0[e]) + bf2f(d0[e]) + (&p0.x)[e];
                h[w5*4+e] = v;
                s += v; ss = fmaf(v, v, ss);
            }
        }
#pragma unroll
        for (int off = 1; off < 16; off <<= 1) {
            s  += __shfl_xor(s,  off);
            ss += __shfl_xor(ss, off);
        }
        const float mu   = s * inv;
        const float rsig = rsqrtf(ss * inv - mu * mu + LN_EPS);
        const float murs = mu * rsig;

        float acc2 = 0.f;
#pragma unroll
        for (int w5 = 0; w5 < 5; ++w5) {
            const int c = w5 * 64 + fl * 4;
            float4 g  = *(const float4*)&SG[c];
            float4 bb = *(const float4*)&SB[c];
            float4 w  = *(const float4*)&SW[c];
#pragma unroll
            for (int e = 0; e < 4; ++e) {
                float t0 = fmaf(fmaf(h[w5*4+e], rsig, -murs), (&g.x)[e], (&bb.x)[e]);
                t0 = t0 > 0.f ? t0 : __expf(t0) - 1.f;
                acc2 = fmaf(t0, (&w.x)[e], acc2);
            }
        }
#pragma unroll
        for (int off = 1; off < 16; off <<= 1) acc2 += __shfl_xor(acc2, off);

        if (fl == 0 && active) {
            const int jb = ii - KWIN < 0 ? 0 : ii - KWIN;
            const int n = rowstart(ii) + (j - jb);
            out[(size_t)b * NC + n] = acc2 + b2v;
            if (b == 0) {
                posout[2 * (size_t)n]     = (float)(ii + 1);
                posout[2 * (size_t)n + 1] = (float)(j + 1);
            }
        }
    }
}

// ---------------------------------------------------------------------------
extern "C" void kernel_launch(void* const* d_in, const int* in_sizes, int n_in,
                              void* d_out, int out_size, void* d_ws, size_t ws_size,
                              hipStream_t stream) {
    const float* h_e     = (const float*)d_in[0];
    const float* h_c     = (const float*)d_in[1];
    const float* h_share = (const float*)d_in[2];
    // d_in[3] = mask (unused)
    const float* pos_W   = (const float*)d_in[4];
    const float* W1      = (const float*)d_in[5];
    const float* b1      = (const float*)d_in[6];
    const float* ln_g    = (const float*)d_in[7];
    const float* ln_b    = (const float*)d_in[8];
    const float* W2      = (const float*)d_in[9];
    const float* b2      = (const float*)d_in[10];

    float* ws   = (float*)d_ws;
    float* prel = ws + PREL_OFF;
    short* Wb   = (short*)(ws + WB_OFF);

    float* out    = (float*)d_out;
    float* posout = out + BNC;

    prep_kernel<<<14 + (2 * WNPAD * WKSTR) / 256, 256, 0, stream>>>(
        pos_W, W1, b1, prel, Wb);

    fused_kernel<<<NB * (L_SEQ / ITILE), 1024, 0, stream>>>(
        h_e, h_c, h_share, Wb, prel, ln_g, ln_b, W2, b2, out, posout);
}

// Round 12
// 131.599 us; speedup vs baseline: 1.1160x; 1.1160x over previous
//
#include <hip/hip_runtime.h>
#include <hip/hip_bf16.h>
#include <math.h>

// Problem constants
#define L_SEQ   1024
#define NB      8
#define H_DIM   300
#define KWIN    5
#define NREL    11          // 2K+1
#define PDIM    50
#define NC      11234       // band pair count for L=1024, K=5
#define BNC     (NB*NC)     // 89872
#define LN_EPS  1e-5f

#define KPAD    320         // K padded with zeros in [300,320)
#define WKSTR   320         // Wb k-stride (shorts)
#define WNPAD   320         // Wb padded n rows

#define ITILE   16          // i rows per block
#define HROWS   26          // hc halo rows: i0-5 .. i0+20
#define ZROW    42          // zero row used for MFMA clamp (rows 42..47 zero)
#define XROWS   64          // 0..15 Ae/he, 16..41 Ac/hc, 42..47 zero,
                            // 48..58 Pb (bf16 prel), 59 ones, 60..63 zero
#define XSTR    328         // X row stride in shorts
#define GSTR    68          // G row stride in floats (64 + 4 pad)
#define NPAIR   (ITILE*NREL)  // 176

// Workspace layout (float offsets)
#define WB_OFF   2048       // prelbf (11*328 shorts = 7216 B) lives at 0
                            // Wb: 2*320*320 shorts = 102400 floats

typedef __attribute__((ext_vector_type(8))) short s16x8;
typedef __attribute__((ext_vector_type(4))) short s16x4;
typedef __attribute__((ext_vector_type(4))) float f32x4;

__device__ __forceinline__ short f2bf(float f) {
    unsigned u = __float_as_uint(f);
    u += 0x7fffu + ((u >> 16) & 1u);
    return (short)(u >> 16);
}
__device__ __forceinline__ float bf2f(short s) {
    return __uint_as_float(((unsigned)(unsigned short)s) << 16);
}

// band row start: first linear index n of row i
__device__ __forceinline__ int rowstart(int i) {
    if (i < 5)     return 6 * i + (i * (i - 1)) / 2;
    if (i <= 1018) return 40 + (i - 5) * 11;
    int d = i - 1019;
    return 11194 + d * 10 - (d * (d - 1)) / 2;
}

// ---------------------------------------------------------------------------
// Kernel 1: prep.
//  blocks 0..14   : prelbf[r][h] = bf16(b1[h] + sum_d W1[h][600+d]*emb11[r][d]),
//                   stride 328, zero pad h>=300
//  blocks 15..814 : Wb[z][n][k] = bf16(W1[n][z*300+k]), zero-padded
__global__ __launch_bounds__(256) void prep_kernel(
    const float* __restrict__ pos_W, const float* __restrict__ W1,
    const float* __restrict__ b1, short* __restrict__ prelbf,
    short* __restrict__ Wb)
{
    if (blockIdx.x < 15) {
        __shared__ float semb[NREL * PDIM];
        for (int t = threadIdx.x; t < NREL * PDIM; t += 256) {
            int r = t / PDIM, d = t % PDIM;
            float acc = 0.f;
#pragma unroll
            for (int r2 = 0; r2 < NREL; ++r2) {
                float cnt = (float)(L_SEQ - abs(r2 - KWIN));
                int dr = r - r2;
                acc += cnt * expf(-(float)(dr * dr)) * pos_W[r2 * PDIM + d];
            }
            semb[t] = acc;
        }
        __syncthreads();
        int t = blockIdx.x * 256 + threadIdx.x;
        if (t < NREL * XSTR) {
            int r = t / XSTR, h = t % XSTR;
            float acc = 0.f;
            if (h < H_DIM) {
                acc = b1[h];
                const float* wrow = W1 + (size_t)h * 650 + 600;
                const float* em = semb + r * PDIM;
#pragma unroll 10
                for (int d = 0; d < PDIM; ++d) acc += wrow[d] * em[d];
            }
            prelbf[t] = (h < H_DIM) ? f2bf(acc) : (short)0;
        }
    } else {
        int id = (blockIdx.x - 15) * 256 + threadIdx.x;
        if (id < 2 * WNPAD * WKSTR) {
            int z = id / (WNPAD * WKSTR);
            int rem = id % (WNPAD * WKSTR);
            int n = rem / WKSTR, k = rem % WKSTR;
            float v = (n < H_DIM && k < H_DIM) ? W1[(size_t)n * 650 + z * H_DIM + k] : 0.f;
            Wb[id] = f2bf(v);
        }
    }
}

// ---------------------------------------------------------------------------
// Kernel 2: fused GEMM + Gram mini-GEMM + epilogue.
// Block = (b, i-tile of 16), 512 threads (8 waves), grid 512.
// LN stats via decomposition: G = X . X^T gives all row sums (ones col),
// row sumsq (diag) and cross dots -> no per-pair stats pass.
__global__ __launch_bounds__(512) void fused_kernel(
    const float* __restrict__ h_e, const float* __restrict__ h_c,
    const float* __restrict__ h_share, const short* __restrict__ Wb,
    const short* __restrict__ prelbf,
    const float* __restrict__ ln_g, const float* __restrict__ ln_b,
    const float* __restrict__ W2, const float* __restrict__ b2,
    float* __restrict__ out, float* __restrict__ posout)
{
    __shared__ __align__(16) short X[XROWS * XSTR];   // 41984 B
    __shared__ __align__(16) float GL[XROWS * GSTR];  // 17408 B
    __shared__ __align__(16) float SG[320];
    __shared__ __align__(16) float SB[320];
    __shared__ __align__(16) float SW[320];

    const int tid = threadIdx.x;
    const int b   = blockIdx.x >> 6;          // 64 i-tiles per batch
    const int i0  = (blockIdx.x & 63) * ITILE;

    // ---- zero-fill: rows 42..47 & 60..63 full width (10*41) + rows 0..41
    // cols [304,328) (42*3) = 536 16B chunks
    for (int t = tid; t < 536; t += 512) {
        int row, c;
        if (t < 410) { int rr2 = t / 41; row = rr2 < 6 ? 42 + rr2 : 60 + (rr2 - 6); c = (t % 41) * 8; }
        else         { int u = t - 410; row = u / 3; c = 304 + (u % 3) * 8; }
        *(s16x8*)&X[row * XSTR + c] = (s16x8){0,0,0,0,0,0,0,0};
    }
    // ---- ones row (59): bf16(1.0)=0x3F80 for cols<300, else 0
    for (int t = tid; t < XSTR; t += 512)
        X[59 * XSTR + t] = (t < H_DIM) ? (short)0x3F80 : (short)0;
    // ---- Pb rows 48..58: straight copy from prelbf (layout matches)
    for (int t = tid; t < NREL * 41; t += 512) {
        int r = t / 41, c = (t % 41) * 8;
        *(s16x8*)&X[(48 + r) * XSTR + c] = *(const s16x8*)(prelbf + r * XSTR + c);
    }
    // ---- LN params to LDS (zero pad to 320)
    if (tid < 320) {
        bool v = tid < H_DIM;
        SG[tid] = v ? ln_g[tid] : 0.f;
        SB[tid] = v ? ln_b[tid] : 0.f;
        SW[tid] = v ? W2[tid]   : 0.f;
    }
    // ---- stage 26 halo rows; h_share read once per row.
    for (int t = tid; t < HROWS * 76; t += 512) {
        int s = t / 76, kc = (t % 76) * 4;
        int g = i0 - KWIN + s;
        bool valid = (kc < H_DIM) && (g >= 0) && (g < L_SEQ);
        float4 hs4 = make_float4(0.f,0.f,0.f,0.f), hc4 = hs4;
        size_t off = 0;
        if (valid) {
            off = ((size_t)b * L_SEQ + g) * H_DIM + kc;
            hs4 = *(const float4*)(h_share + off);
            hc4 = *(const float4*)(h_c + off);
        }
        s16x4 vc = { f2bf(hc4.x + hs4.x), f2bf(hc4.y + hs4.y),
                     f2bf(hc4.z + hs4.z), f2bf(hc4.w + hs4.w) };
        *(s16x4*)&X[(16 + s) * XSTR + kc] = vc;
        if (s >= 5 && s < 5 + ITILE) {         // he row: g = i0 + (s-5)
            float4 he4 = make_float4(0.f,0.f,0.f,0.f);
            if (valid) he4 = *(const float4*)(h_e + off);
            s16x4 ve = { f2bf(he4.x + hs4.x), f2bf(he4.y + hs4.y),
                         f2bf(he4.z + hs4.z), f2bf(he4.w + hs4.w) };
            *(s16x4*)&X[(s - 5) * XSTR + kc] = ve;
        }
    }
    __syncthreads();

    // ---- Main GEMM (r5 structure). 8 waves: wz = wave>>2, nsl = (wave&3)*80.
    const int wave = tid >> 6, lane = tid & 63;
    const int fr = lane & 15, fq = lane >> 4;
    const int wz  = wave >> 2;
    const int nsl = (wave & 3) * 80;
    const short* wbase = Wb + ((size_t)(wz * WNPAD + nsl + fr)) * WKSTR + fq * 8;

    const int mrow0 = wz ? (16 + fr) : fr;
    const int mrow1 = (fr < 10) ? (32 + fr) : ZROW;   // wz==1 only

    f32x4 acc0[5] = {};
    f32x4 acc1[5] = {};

    for (int k0 = 0; k0 < KPAD; k0 += 32) {
        s16x8 bf[5];
#pragma unroll
        for (int nt = 0; nt < 5; ++nt)
            bf[nt] = *(const s16x8*)(wbase + (size_t)nt * 16 * WKSTR + k0);
        s16x8 af0 = *(const s16x8*)&X[mrow0 * XSTR + k0 + fq * 8];
#pragma unroll
        for (int nt = 0; nt < 5; ++nt)
            acc0[nt] = __builtin_amdgcn_mfma_f32_16x16x32_bf16(af0, bf[nt], acc0[nt], 0, 0, 0);
        if (wz) {
            s16x8 af1 = *(const s16x8*)&X[mrow1 * XSTR + k0 + fq * 8];
#pragma unroll
            for (int nt = 0; nt < 5; ++nt)
                acc1[nt] = __builtin_amdgcn_mfma_f32_16x16x32_bf16(af1, bf[nt], acc1[nt], 0, 0, 0);
        }
    }
    __syncthreads();   // all waves done reading X inputs

    // ---- write Ae/Ac into X (bf16). C/D: col = nsl+nt*16+fr, row = fq*4+r2
#pragma unroll
    for (int nt = 0; nt < 5; ++nt) {
        const int col = nsl + nt * 16 + fr;     // cols>=300 compute to 0
        if (!wz) {
#pragma unroll
            for (int r2 = 0; r2 < 4; ++r2)
                X[(fq * 4 + r2) * XSTR + col] = f2bf(acc0[nt][r2]);
        } else {
#pragma unroll
            for (int r2 = 0; r2 < 4; ++r2)
                X[(16 + fq * 4 + r2) * XSTR + col] = f2bf(acc0[nt][r2]);
#pragma unroll
            for (int r2 = 0; r2 < 4; ++r2) {
                int rw = 32 + fq * 4 + r2;
                if (rw < 42) X[rw * XSTR + col] = f2bf(acc1[nt][r2]);
            }
        }
    }
    __syncthreads();

    // ---- Gram mini-GEMM: G = X . X^T over 64 rows (k = 320).
    // Wave w: mf = w&3, nf0 = (w>>2)*2 -> frags (mf,nf0),(mf,nf0+1).
    {
        const int mf  = wave & 3;
        const int nf0 = (wave >> 2) * 2;
        f32x4 ga = {}, gb = {};
        for (int k0 = 0; k0 < KPAD; k0 += 32) {
            s16x8 av = *(const s16x8*)&X[(mf * 16 + fr) * XSTR + k0 + fq * 8];
            s16x8 b0 = *(const s16x8*)&X[(nf0 * 16 + fr) * XSTR + k0 + fq * 8];
            s16x8 b1 = *(const s16x8*)&X[((nf0 + 1) * 16 + fr) * XSTR + k0 + fq * 8];
            ga = __builtin_amdgcn_mfma_f32_16x16x32_bf16(av, b0, ga, 0, 0, 0);
            gb = __builtin_amdgcn_mfma_f32_16x16x32_bf16(av, b1, gb, 0, 0, 0);
        }
#pragma unroll
        for (int r2 = 0; r2 < 4; ++r2) {
            GL[(mf * 16 + fq * 4 + r2) * GSTR + nf0 * 16 + fr]        = ga[r2];
            GL[(mf * 16 + fq * 4 + r2) * GSTR + (nf0 + 1) * 16 + fr]  = gb[r2];
        }
    }
    __syncthreads();

    // ---- Epilogue: 1 pair per 16-lane quad, 32 quads, 6 rounds (176 pairs).
    // Stats from G; single norm+ELU+dot pass; one 4-step shuffle chain.
    const int quad = lane >> 4, fl = lane & 15;
    const int qq = wave * 4 + quad;            // 0..31
    const float b2v = b2[0];
    const float inv = 1.f / (float)H_DIM;

    for (int round = 0; round < 6; ++round) {
        const int q = round * 32 + qq;          // 0..191
        const int qc = q < NPAIR - 1 ? q : NPAIR - 1;
        const int di = qc / NREL, rr = qc % NREL;
        const int ii = i0 + di, j = ii - KWIN + rr;
        const bool active = (q < NPAIR) && (j >= 0) && (j < L_SEQ);

        const int iA = di;                 // Ae row in X/G
        const int jA = 16 + di + rr;       // Ac row
        const int pA = 48 + rr;            // Pb row

        const float Se  = GL[iA * GSTR + 59];
        const float Sc  = GL[jA * GSTR + 59];
        const float Sp  = GL[pA * GSTR + 59];
        const float SSe = GL[iA * GSTR + iA];
        const float SSc = GL[jA * GSTR + jA];
        const float SSp = GL[pA * GSTR + pA];
        const float Dec = GL[iA * GSTR + jA];
        const float Dep = GL[iA * GSTR + pA];
        const float Dcp = GL[jA * GSTR + pA];

        const float mu   = (Se + Sc + Sp) * inv;
        const float ss   = SSe + SSc + SSp + 2.f * (Dec + Dep + Dcp);
        const float rsig = rsqrtf(ss * inv - mu * mu + LN_EPS);
        const float nmrs = -mu * rsig;

        const int ea = iA * XSTR, ca = jA * XSTR, pa = pA * XSTR;

        float acc2 = 0.f;
#pragma unroll
        for (int w5 = 0; w5 < 5; ++w5) {
            const int c = w5 * 64 + fl * 4;     // 0..316, zero-padded
            s16x4 a0 = *(const s16x4*)&X[ea + c];
            s16x4 d0 = *(const s16x4*)&X[ca + c];
            s16x4 p0 = *(const s16x4*)&X[pa + c];
            float4 g  = *(const float4*)&SG[c];
            float4 bb = *(const float4*)&SB[c];
            float4 w  = *(const float4*)&SW[c];
#pragma unroll
            for (int e = 0; e < 4; ++e) {
                float v = bf2f(a0[e]) + bf2f(d0[e]) + bf2f(p0[e]);
                float t0 = fmaf(fmaf(v, rsig, nmrs), (&g.x)[e], (&bb.x)[e]);
                t0 = t0 > 0.f ? t0 : __expf(t0) - 1.f;
                acc2 = fmaf(t0, (&w.x)[e], acc2);
            }
        }
#pragma unroll
        for (int off = 1; off < 16; off <<= 1) acc2 += __shfl_xor(acc2, off);

        if (fl == 0 && active) {
            const int jb = ii - KWIN < 0 ? 0 : ii - KWIN;
            const int n = rowstart(ii) + (j - jb);
            out[(size_t)b * NC + n] = acc2 + b2v;
            if (b == 0) {
                posout[2 * (size_t)n]     = (float)(ii + 1);
                posout[2 * (size_t)n + 1] = (float)(j + 1);
            }
        }
    }
}

// ---------------------------------------------------------------------------
extern "C" void kernel_launch(void* const* d_in, const int* in_sizes, int n_in,
                              void* d_out, int out_size, void* d_ws, size_t ws_size,
                              hipStream_t stream) {
    const float* h_e     = (const float*)d_in[0];
    const float* h_c     = (const float*)d_in[1];
    const float* h_share = (const float*)d_in[2];
    // d_in[3] = mask (unused)
    const float* pos_W   = (const float*)d_in[4];
    const float* W1      = (const float*)d_in[5];
    const float* b1      = (const float*)d_in[6];
    const float* ln_g    = (const float*)d_in[7];
    const float* ln_b    = (const float*)d_in[8];
    const float* W2      = (const float*)d_in[9];
    const float* b2      = (const float*)d_in[10];

    float* ws     = (float*)d_ws;
    short* prelbf = (short*)ws;
    short* Wb     = (short*)(ws + WB_OFF);

    float* out    = (float*)d_out;
    float* posout = out + BNC;

    prep_kernel<<<15 + (2 * WNPAD * WKSTR) / 256, 256, 0, stream>>>(
        pos_W, W1, b1, prelbf, Wb);

    fused_kernel<<<NB * (L_SEQ / ITILE), 512, 0, stream>>>(
        h_e, h_c, h_share, Wb, prelbf, ln_g, ln_b, W2, b2, out, posout);
}